// Round 8
// baseline (146.968 us; speedup 1.0000x reference)
//
#include <hip/hip_runtime.h>

#define NCH 120

typedef int i32x4 __attribute__((ext_vector_type(4)));

// ---------------------------------------------------------------------------
// Prep kernel (1 block, 128 threads), two-phase (validated R7):
//  phase 1: rows 0..119 of wb_i8[128][128] = sign(conv_w) in {-1,0,+1};
//           rows 120..127 zeroed.
//  phase 2: row 120 byte k = wsum[k] = sum_c sign(conv_w[c][k])  (free-S1 row)
//  coef[128] float4 = {conv_b, gn_w, gn_b, lin_w}; pads {0,1,0,0}.
//  ws layout: [0,16384) wb_i8; [16384,18432) coef.
// ---------------------------------------------------------------------------
__global__ void prep_kernel(const float* __restrict__ conv_w,
                            const float* __restrict__ conv_b,
                            const float* __restrict__ gn_w,
                            const float* __restrict__ gn_b,
                            const float* __restrict__ lin_w,
                            unsigned char* __restrict__ wsb)
{
    const int c = threadIdx.x;            // 0..127
    if (c >= 128) return;
    unsigned* row32 = (unsigned*)(wsb + c * 128);
    if (c < NCH) {
        for (int kw = 0; kw < 32; ++kw) {
            unsigned pk = 0u;
            for (int b = 0; b < 4; ++b) {
                const int k = kw * 4 + b;
                unsigned v = 0u;
                if (k < NCH) {
                    const float w = conv_w[c * NCH + k];
                    v = (w > 0.0f) ? 0x01u : ((w < 0.0f) ? 0xFFu : 0x00u);
                }
                pk |= v << (8 * b);
            }
            row32[kw] = pk;
        }
    } else {
        for (int kw = 0; kw < 32; ++kw) row32[kw] = 0u;
    }
    __syncthreads();   // phase-1 global writes visible block-wide

    {   // phase 2: thread k sums column k of the binarized rows (parallel)
        int s = 0;
        if (c < NCH)
            for (int r = 0; r < NCH; ++r)
                s += (int)(signed char)wsb[r * 128 + c];
        wsb[120 * 128 + c] = (unsigned char)((unsigned)s & 0xFFu);
    }

    float4 o;
    o.x = (c < NCH) ? conv_b[c] : 0.0f;
    o.y = (c < NCH) ? gn_w[c]   : 1.0f;
    o.z = (c < NCH) ? gn_b[c]   : 0.0f;
    o.w = (c < NCH) ? lin_w[c]  : 0.0f;
    ((float4*)(wsb + 16384))[c] = o;
}

// Binarize 4 floats against 0.5 into 4 packed i8 in {+1, 0, -1}.
// sign(x-0.5): +1 if x>0.5, -1 if x<0.5, 0 if x==0.5 exactly.
__device__ __forceinline__ unsigned cvt4(float4 v) {
    unsigned b0 = (v.x > 0.5f) ? 0x01u : ((v.x < 0.5f) ? 0xFFu : 0x00u);
    unsigned b1 = (v.y > 0.5f) ? 0x01u : ((v.y < 0.5f) ? 0xFFu : 0x00u);
    unsigned b2 = (v.z > 0.5f) ? 0x01u : ((v.z < 0.5f) ? 0xFFu : 0x00u);
    unsigned b3 = (v.w > 0.5f) ? 0x01u : ((v.w < 0.5f) ? 0xFFu : 0x00u);
    return b0 | (b1 << 8) | (b2 << 16) | (b3 << 24);
}

// ---------------------------------------------------------------------------
// Main kernel, v8: coalesced staging -> binarized-i8 LDS tile -> i8 MFMA.
//  - Staging (per 64-sample tile = 7680 floats = 30720B): 256 threads make
//    7.5 rounds of LINEAR lane-contiguous float4 loads (1KB/wave/instr, the
//    same pattern the 6.6TB/s fills use), cvt4 in-register, 4B ds_write.
//    LDS tile = 7680 i8 = the A-fragment bytes directly.
//  - Double-buffered (2x7.5KB), ONE barrier/iter (write n+2 is fenced from
//    read n by barrier n+1).  Next tile's float4s prefetched into registers
//    before compute; cvt4 after compute (HBM latency hidden under MFMA).
//  - Compute identical to validated v7: afrag = ds_read_b64 at
//    row*120 + kc*32 + lg*8 (pad chunk kc==3,lg==3 zeroed); B-frags in
//    VGPRs; S1 free from GEMM col 120 (wsum row); S2 16-lane butterfly;
//    exact-integer stats; fp32 norm+affine+softsign+lin_w dot.
// ---------------------------------------------------------------------------
__global__ __launch_bounds__(256) void bnn_kernel(
    const float* __restrict__ x,
    const unsigned char* __restrict__ wsb,
    float* __restrict__ out,
    int B, int num_tiles, int tiles_per_block)
{
    __shared__ __align__(16) unsigned char s_xb[2][7680];
    __shared__ float4 s_cf[128];

    const int tid  = threadIdx.x;
    const int lane = tid & 63;
    const int wv   = tid >> 6;
    const int l15  = lane & 15;
    const int lg   = lane >> 4;            // 0..3
    const bool padlane = (lg == 3);        // k=120..127 pad within kc==3

    if (tid < 128) s_cf[tid] = ((const float4*)(wsb + 16384))[tid];

    // ---- B fragments: loaded once, kept in VGPRs (8 col-tiles x 4 k-chunks)
    long bfrag[8][4];
#pragma unroll
    for (int t = 0; t < 8; ++t)
#pragma unroll
        for (int kc = 0; kc < 4; ++kc)
            bfrag[t][kc] = *(const long*)(wsb + (t * 16 + l15) * 128 + kc * 32 + lg * 8);

    const long long maxf4 = (long long)B * 30 - 1;   // last valid float4 index

    // ---- prologue: load + binarize tile 0 into sx ----
    unsigned sx[8];
    {
        const long long t0 = (long long)blockIdx.x * 1920;
#pragma unroll
        for (int r = 0; r < 8; ++r) {
            if (r < 7 || tid < 128) {
                long long f4 = t0 + r * 256 + tid;
                if (f4 > maxf4) f4 = maxf4;
                sx[r] = cvt4(*(const float4*)(x + f4 * 4));
            }
        }
    }

    int cur = 0;
    for (int it = 0; it < tiles_per_block; ++it) {
        const int tile = blockIdx.x + it * gridDim.x;
        if (tile >= num_tiles) break;
        const long long s0 = (long long)tile * 64 + wv * 16;

        // ---- write staged i8 to LDS buf[cur] (linear, conflict-free) ----
        unsigned* dst = (unsigned*)s_xb[cur];
#pragma unroll
        for (int r = 0; r < 8; ++r)
            if (r < 7 || tid < 128) dst[r * 256 + tid] = sx[r];

        // ---- issue next tile's loads (float4s land during compute) ----
        float4 fr[8];
        const int nt = blockIdx.x + (it + 1) * gridDim.x;
        const bool havenext = (it + 1 < tiles_per_block) && (nt < num_tiles);
        if (havenext) {
            const long long tb = (long long)nt * 1920;
#pragma unroll
            for (int r = 0; r < 8; ++r) {
                if (r < 7 || tid < 128) {
                    long long f4 = tb + r * 256 + tid;
                    if (f4 > maxf4) f4 = maxf4;
                    fr[r] = *(const float4*)(x + f4 * 4);
                }
            }
        }

        __syncthreads();   // buf[cur] complete; also fences next writes

        // ---- A fragments straight from the i8 LDS tile ----
        const unsigned char* rowp = s_xb[cur] + (wv * 16 + l15) * 120 + lg * 8;
        long afrag[4];
#pragma unroll
        for (int kc = 0; kc < 4; ++kc)
            afrag[kc] = *(const long*)(rowp + kc * 32);
        if (padlane) afrag[3] = 0;          // k=120..127 pad

        // ---- MFMA: 4 k-chunks x 8 col-tiles ----
        i32x4 acc[8];
#pragma unroll
        for (int t = 0; t < 8; ++t) acc[t] = (i32x4){0, 0, 0, 0};
#pragma unroll
        for (int kc = 0; kc < 4; ++kc)
#pragma unroll
            for (int t = 0; t < 8; ++t)
                acc[t] = __builtin_amdgcn_mfma_i32_16x16x32_i8(
                    afrag[kc], bfrag[t][kc], acc[t], 0, 0, 0);

        // ---- stats: S1 free from col 120; S2 via 16-lane butterfly ----
        int S2[4] = {0, 0, 0, 0};
#pragma unroll
        for (int t = 0; t < 8; ++t)
#pragma unroll
            for (int q = 0; q < 4; ++q) {
                int y = acc[t][q];
                if (t == 7) y = (l15 == 8) ? 0 : y;   // exclude S1 col
                S2[q] += y * y;
            }
#pragma unroll
        for (int m = 1; m <= 8; m <<= 1)
#pragma unroll
            for (int q = 0; q < 4; ++q)
                S2[q] += __shfl_xor(S2[q], m, 64);

        float rstd[4], nb[4];
#pragma unroll
        for (int q = 0; q < 4; ++q) {
            const int s1 = __shfl(acc[7][q], (lane & 48) | 8, 64);  // col 120
            const float mean = (float)s1 * (1.0f / 120.0f);
            const float var  = (float)S2[q] * (1.0f / 120.0f) - mean * mean;
            rstd[q] = __builtin_amdgcn_rsqf(var + 1e-5f);
            nb[q]   = -mean * rstd[q];
        }

        // ---- epilogue: norm + affine + softsign + lin_w dot ----
        float d[4] = {0.0f, 0.0f, 0.0f, 0.0f};
#pragma unroll
        for (int t = 0; t < 8; ++t) {
            const float4 cf = s_cf[t * 16 + l15];
#pragma unroll
            for (int q = 0; q < 4; ++q) {
                const float yf = (float)acc[t][q] + cf.x;      // + conv_b
                const float n  = fmaf(yf, rstd[q], nb[q]);     // groupnorm
                const float g  = fmaf(n, cf.y, cf.z);          // *gn_w+gn_b
                const float s  = g * __builtin_amdgcn_rcpf(1.0f + fabsf(g));
                d[q] = fmaf(s, cf.w, d[q]);                    // dot lin_w
            }
        }
#pragma unroll
        for (int m = 1; m <= 8; m <<= 1)
#pragma unroll
            for (int q = 0; q < 4; ++q)
                d[q] += __shfl_xor(d[q], m, 64);

        if (l15 == 0) {
#pragma unroll
            for (int q = 0; q < 4; ++q) {
                const long long o = s0 + lg * 4 + q;           // row=lg*4+q
                if (o < (long long)B) out[o] = d[q];
            }
        }

        // ---- binarize the prefetched tile for the next iteration ----
        if (havenext) {
#pragma unroll
            for (int r = 0; r < 8; ++r)
                if (r < 7 || tid < 128) sx[r] = cvt4(fr[r]);
        }
        cur ^= 1;
    }
}

extern "C" void kernel_launch(void* const* d_in, const int* in_sizes, int n_in,
                              void* d_out, int out_size, void* d_ws, size_t ws_size,
                              hipStream_t stream) {
    const float* x      = (const float*)d_in[0];
    const float* conv_w = (const float*)d_in[1];
    const float* conv_b = (const float*)d_in[2];
    const float* gn_w   = (const float*)d_in[3];
    const float* gn_b   = (const float*)d_in[4];
    const float* lin_w  = (const float*)d_in[5];
    unsigned char* wsb = (unsigned char*)d_ws;
    float* out = (float*)d_out;

    const int B = in_sizes[0] / NCH;
    prep_kernel<<<1, 128, 0, stream>>>(conv_w, conv_b, gn_w, gn_b, lin_w, wsb);

    const int num_tiles = (B + 63) / 64;
    const int grid = num_tiles < 2048 ? num_tiles : 2048;
    const int tiles_per_block = (num_tiles + grid - 1) / grid;
    bnn_kernel<<<grid, 256, 0, stream>>>(x, wsb, out, B, num_tiles, tiles_per_block);
}